// Round 1
// baseline (282.440 us; speedup 1.0000x reference)
//
#include <hip/hip_runtime.h>
#include <stdint.h>

#define NN 4096      // nodes
#define EE 131072    // edges
#define IND 1024
#define OUTD 512
#define NH 4

typedef __bf16 bf16x8 __attribute__((ext_vector_type(8)));
typedef float f32x4 __attribute__((ext_vector_type(4)));

__device__ __forceinline__ unsigned short f2bf(float f) {
  unsigned u = __float_as_uint(f);
  u += 0x7FFFu + ((u >> 16) & 1u);   // RNE, data has no NaN
  return (unsigned short)(u >> 16);
}

// ---------------- K1a: cast x -> bf16 ----------------
__global__ void cast_x_kernel(const float* __restrict__ x, unsigned short* __restrict__ xb) {
  int i = blockIdx.x * 256 + threadIdx.x;         // 4 elems/thread
  float4 v = ((const float4*)x)[i];
  ushort4 o;
  o.x = f2bf(v.x); o.y = f2bf(v.y); o.z = f2bf(v.z); o.w = f2bf(v.w);
  ((ushort4*)xb)[i] = o;
}

// ---------------- K1b: W[h][i][o] f32 -> Wt[h][o][i] bf16 (transpose) ----------------
__global__ void transpose_w_kernel(const float* __restrict__ W, unsigned short* __restrict__ Wt) {
  __shared__ float tile[32][33];
  int i0 = blockIdx.x * 32, o0 = blockIdx.y * 32, h = blockIdx.z;
  int tx = threadIdx.x, ty = threadIdx.y;
#pragma unroll
  for (int r = 0; r < 32; r += 8)
    tile[ty + r][tx] = W[((size_t)(h * IND + i0 + ty + r)) * OUTD + o0 + tx];
  __syncthreads();
#pragma unroll
  for (int r = 0; r < 32; r += 8)
    Wt[((size_t)(h * OUTD + o0 + ty + r)) * IND + i0 + tx] = f2bf(tile[tx][ty + r]);
}

// ---------------- K2: bf16 MFMA GEMM, 128x128 tile, BK=32, 2-phase dbuf ----------------
__device__ __forceinline__ void gload16(const unsigned short* g, unsigned short* l) {
  __builtin_amdgcn_global_load_lds((const __attribute__((address_space(1))) void*)g,
                                   (__attribute__((address_space(3))) void*)l, 16, 0, 0);
}

__global__ __launch_bounds__(256, 2) void gemm_kernel(
    const unsigned short* __restrict__ X, const unsigned short* __restrict__ Wt,
    float* __restrict__ Hf, unsigned short* __restrict__ Hb) {
  __shared__ __align__(16) unsigned short As[2][4096];  // [128 rows][32 k] bf16, XOR-swizzled
  __shared__ __align__(16) unsigned short Bs[2][4096];  // [128 n-rows][32 k]
  const int t = threadIdx.x, w = t >> 6, lane = t & 63;
  const int bx = blockIdx.x, by = blockIdx.y, hh = blockIdx.z;

  const unsigned short* Ab0 = X + (size_t)(by * 128) * IND;
  const unsigned short* Bb0 = Wt + (size_t)(hh * OUTD + bx * 128) * IND;

  // staging map: seg (0..511) -> row=seg>>2, colseg=(seg&3)^(row&3) [both-sides swizzle]
  const int seg0 = w * 64 + lane, seg1 = (4 + w) * 64 + lane;
  const int r0 = seg0 >> 2, c0 = (seg0 & 3) ^ (r0 & 3);
  const int r1 = seg1 >> 2, c1 = (seg1 & 3) ^ (r1 & 3);

  // fragment read byte offsets (per 16B granule, same XOR)
  const int wr = w >> 1, wc = w & 1, g = lane >> 4, rlo = lane & 15;
  int aoff[4], boff[4];
#pragma unroll
  for (int i = 0; i < 4; i++) {
    int ra = wr * 64 + i * 16 + rlo;
    aoff[i] = ra * 64 + ((g ^ (ra & 3)) << 4);
    int rb = wc * 64 + i * 16 + rlo;
    boff[i] = rb * 64 + ((g ^ (rb & 3)) << 4);
  }

  f32x4 zero = {0.f, 0.f, 0.f, 0.f};
  f32x4 acc[4][4];
#pragma unroll
  for (int i = 0; i < 4; i++)
#pragma unroll
    for (int j = 0; j < 4; j++) acc[i][j] = zero;

#define STAGE(buf, kt)                                                   \
  do {                                                                   \
    const unsigned short* ga = Ab0 + (kt) * 32;                          \
    const unsigned short* gb = Bb0 + (kt) * 32;                          \
    gload16(ga + r0 * IND + c0 * 8, &As[buf][w * 512]);                  \
    gload16(ga + r1 * IND + c1 * 8, &As[buf][(4 + w) * 512]);            \
    gload16(gb + r0 * IND + c0 * 8, &Bs[buf][w * 512]);                  \
    gload16(gb + r1 * IND + c1 * 8, &Bs[buf][(4 + w) * 512]);            \
  } while (0)

  STAGE(0, 0);
  __syncthreads();
  int cur = 0;
  for (int kt = 0; kt < 32; ++kt) {
    if (kt != 31) STAGE(cur ^ 1, kt + 1);
    const char* Abuf = (const char*)As[cur];
    const char* Bbuf = (const char*)Bs[cur];
    bf16x8 av[4], bv[4];
#pragma unroll
    for (int i = 0; i < 4; i++) {
      av[i] = *(const bf16x8*)(Abuf + aoff[i]);
      bv[i] = *(const bf16x8*)(Bbuf + boff[i]);
    }
#pragma unroll
    for (int i = 0; i < 4; i++)
#pragma unroll
      for (int j = 0; j < 4; j++)
        acc[i][j] = __builtin_amdgcn_mfma_f32_16x16x32_bf16(av[i], bv[j], acc[i][j], 0, 0, 0);
    __syncthreads();
    cur ^= 1;
  }
#undef STAGE

  // epilogue: C/D layout col=lane&15, row=(lane>>4)*4+q  [m89/m91 verified]
  const size_t outbase = (size_t)hh * NN * OUTD;
#pragma unroll
  for (int i = 0; i < 4; i++)
#pragma unroll
    for (int j = 0; j < 4; j++) {
      int mm0 = by * 128 + wr * 64 + i * 16 + g * 4;
      int nn = bx * 128 + wc * 64 + j * 16 + rlo;
#pragma unroll
      for (int q = 0; q < 4; q++) {
        size_t off = outbase + (size_t)(mm0 + q) * OUTD + nn;
        float v = acc[i][j][q];
        Hf[off] = v;
        Hb[off] = f2bf(v);
      }
    }
}

// ---------------- K3a: s_src/s_dst = h . a  (one wave per (h,n)) ----------------
__global__ void s_kernel(const float* __restrict__ Hf, const float* __restrict__ a,
                         float* __restrict__ s_src, float* __restrict__ s_dst) {
  int wid = (blockIdx.x * 256 + threadIdx.x) >> 6;
  int lane = threadIdx.x & 63;
  int h = wid >> 12, n = wid & 4095;
  const float4* hp = (const float4*)(Hf + ((size_t)(h * NN + n)) * OUTD);
  const float4* as = (const float4*)(a + h * 2 * OUTD);
  const float4* ad = (const float4*)(a + h * 2 * OUTD + OUTD);
  float ss = 0.f, sd = 0.f;
#pragma unroll
  for (int k = 0; k < 2; k++) {
    float4 hv = hp[lane * 2 + k];
    float4 av = as[lane * 2 + k];
    float4 dv = ad[lane * 2 + k];
    ss += hv.x * av.x + hv.y * av.y + hv.z * av.z + hv.w * av.w;
    sd += hv.x * dv.x + hv.y * dv.y + hv.z * dv.z + hv.w * dv.w;
  }
#pragma unroll
  for (int m = 1; m < 64; m <<= 1) {
    ss += __shfl_xor(ss, m);
    sd += __shfl_xor(sd, m);
  }
  if (lane == 0) {
    s_src[h * NN + n] = ss;
    s_dst[h * NN + n] = sd;
  }
}

// ---------------- K3b: S[h][o] = column sum of Hf ----------------
__global__ void colsum_kernel(const float* __restrict__ Hf, float* __restrict__ S) {
  int h = blockIdx.x >> 4, chunk = blockIdx.x & 15;
  int t = threadIdx.x;
  const float* base = Hf + ((size_t)h * NN + chunk * 256) * OUTD;
  float a0 = 0.f, a1 = 0.f;
  for (int r = 0; r < 256; r++) {
    a0 += base[(size_t)r * OUTD + t];
    a1 += base[(size_t)r * OUTD + 256 + t];
  }
  atomicAdd(&S[h * OUTD + t], a0);
  atomicAdd(&S[h * OUTD + 256 + t], a1);
}

// ---------------- K4: edge pass A — dedup, counts, row max ----------------
__global__ void edge_a_kernel(const int* __restrict__ ei, const float* __restrict__ s_src,
                              const float* __restrict__ s_dst, unsigned* __restrict__ bitmap,
                              int* __restrict__ counts, int* __restrict__ flags,
                              unsigned* __restrict__ mmax) {
  int e = blockIdx.x * 256 + threadIdx.x;
  int row = ei[e], col = ei[EE + e];
  unsigned key = ((unsigned)row << 12) | (unsigned)col;
  unsigned bit = 1u << (key & 31);
  unsigned old = atomicOr(&bitmap[key >> 5], bit);
  if (old & bit) { flags[e] = 1; return; }   // duplicate (same e value -> any winner ok)
  flags[e] = 0;
  atomicAdd(&counts[row], 1);
#pragma unroll
  for (int h = 0; h < NH; h++) {
    float eh = s_src[h * NN + row] + s_dst[h * NN + col];
    eh = eh > 0.f ? eh : 0.2f * eh;
    if (eh > 0.f) atomicMax(&mmax[h * NN + row], __float_as_uint(eh)); // nonneg floats: uint-monotone
  }
}

// ---------------- K5: exclusive scan of counts (single block) ----------------
__global__ void scan_kernel(const int* __restrict__ counts, int* __restrict__ offsets,
                            int* __restrict__ cursor) {
  __shared__ int part[256];
  int t = threadIdx.x;
  int local[16];
  int s = 0;
#pragma unroll
  for (int k = 0; k < 16; k++) { local[k] = counts[t * 16 + k]; s += local[k]; }
  part[t] = s;
  __syncthreads();
  if (t == 0) {
    int run = 0;
    for (int i = 0; i < 256; i++) { int v = part[i]; part[i] = run; run += v; }
  }
  __syncthreads();
  int off = part[t];
#pragma unroll
  for (int k = 0; k < 16; k++) {
    offsets[t * 16 + k] = off;
    cursor[t * 16 + k] = off;
    off += local[k];
  }
}

// ---------------- K6: edge pass B — CSR scatter + g coeffs + T sums ----------------
__global__ void edge_b_kernel(const int* __restrict__ ei, const int* __restrict__ flags,
                              const float* __restrict__ s_src, const float* __restrict__ s_dst,
                              const unsigned* __restrict__ mmax, int* __restrict__ cursor,
                              int* __restrict__ csr_col, float* __restrict__ csr_g,
                              float* __restrict__ Tacc) {
  int e = blockIdx.x * 256 + threadIdx.x;
  if (flags[e]) return;
  int row = ei[e], col = ei[EE + e];
  int pos = atomicAdd(&cursor[row], 1);
  csr_col[pos] = col;
#pragma unroll
  for (int h = 0; h < NH; h++) {
    float eh = s_src[h * NN + row] + s_dst[h * NN + col];
    eh = eh > 0.f ? eh : 0.2f * eh;
    float mm = __uint_as_float(mmax[h * NN + row]);
    float gg = expf(eh - mm) - expf(-mm);
    csr_g[h * EE + pos] = gg;
    atomicAdd(&Tacc[h * NN + row], gg);
  }
}

// ---------------- K7: finalize — h' = (c*S + sum g*h[col]) / D, transposed out ----------------
__global__ __launch_bounds__(256) void finalize_kernel(
    const unsigned short* __restrict__ Hb, const float* __restrict__ S,
    const unsigned* __restrict__ mmax, const float* __restrict__ Tacc,
    const int* __restrict__ offsets, const int* __restrict__ counts,
    const int* __restrict__ csr_col, const float* __restrict__ csr_g,
    float* __restrict__ out) {
  __shared__ int cols_s[64];
  __shared__ float g_s[4][64];
  int i = blockIdx.x, t = threadIdx.x;
  float c[NH], inv[NH];
#pragma unroll
  for (int h = 0; h < NH; h++) {
    float mm = __uint_as_float(mmax[h * NN + i]);
    float ch = expf(-mm);
    float D = (float)NN * ch + Tacc[h * NN + i];
    c[h] = ch;
    inv[h] = 1.0f / D;
  }
  float acc[NH][2];
#pragma unroll
  for (int h = 0; h < NH; h++) {
    acc[h][0] = c[h] * S[h * OUTD + 2 * t];
    acc[h][1] = c[h] * S[h * OUTD + 2 * t + 1];
  }
  int start = offsets[i], cnt = counts[i];
  for (int base = 0; base < cnt; base += 64) {
    int nload = min(64, cnt - base);
    if (t < 64) cols_s[t] = (t < nload) ? csr_col[start + base + t] : 0;
    {
      int hh = t >> 6, kk = t & 63;
      g_s[hh][kk] = (kk < nload) ? csr_g[hh * EE + start + base + kk] : 0.f;
    }
    __syncthreads();
    for (int k = 0; k < nload; k++) {
      int cc = cols_s[k];
#pragma unroll
      for (int h = 0; h < NH; h++) {
        unsigned u = *(const unsigned*)(Hb + ((size_t)(h * NN + cc)) * OUTD + 2 * t);
        float lo = __uint_as_float(u << 16);
        float hi = __uint_as_float(u & 0xffff0000u);
        float gg = g_s[h][k];
        acc[h][0] += gg * lo;
        acc[h][1] += gg * hi;
      }
    }
    __syncthreads();
  }
#pragma unroll
  for (int h = 0; h < NH; h++) {
    float2 st;
    st.x = acc[h][0] * inv[h];
    st.y = acc[h][1] * inv[h];
    *(float2*)(out + (size_t)i * (NH * OUTD) + h * OUTD + 2 * t) = st;
  }
}

extern "C" void kernel_launch(void* const* d_in, const int* in_sizes, int n_in,
                              void* d_out, int out_size, void* d_ws, size_t ws_size,
                              hipStream_t stream) {
  const float* x = (const float*)d_in[0];
  const int* ei = (const int*)d_in[1];
  const float* W = (const float*)d_in[2];
  const float* a = (const float*)d_in[3];
  float* out = (float*)d_out;

  char* ws = (char*)d_ws;
  unsigned short* xb = (unsigned short*)(ws);                       // 8 MB
  unsigned short* wt = (unsigned short*)(ws + (8ull << 20));        // 4 MB
  float* Hf = (float*)(ws + (12ull << 20));                         // 32 MB
  unsigned short* Hb = (unsigned short*)(ws + (44ull << 20));       // 16 MB
  float* s_src = (float*)(ws + (60ull << 20));                      // 64 KB
  float* s_dst = (float*)(ws + (60ull << 20) + 1 * 65536);          // 64 KB
  unsigned* mmax = (unsigned*)(ws + (60ull << 20) + 2 * 65536);     // 64 KB (zeroed)
  float* Tacc = (float*)(ws + (60ull << 20) + 3 * 65536);           // 64 KB (zeroed)
  float* Scol = (float*)(ws + (60ull << 20) + 4 * 65536);           // 8 KB (zeroed)
  int* flags = (int*)(ws + (63ull << 20));                          // 512 KB
  unsigned* bitmap = (unsigned*)(ws + (64ull << 20));               // 2 MB (zeroed)
  int* counts = (int*)(ws + (66ull << 20));                         // 16 KB (zeroed)
  int* offsets = (int*)(ws + (66ull << 20) + 65536);                // 16 KB
  int* cursor = (int*)(ws + (66ull << 20) + 2 * 65536);             // 16 KB
  int* csr_col = (int*)(ws + (67ull << 20));                        // 512 KB
  float* csr_g = (float*)(ws + (68ull << 20));                      // 2 MB   (total 70 MB)

  hipMemsetAsync(bitmap, 0, (size_t)NN * NN / 8, stream);
  hipMemsetAsync(mmax, 0, NH * NN * 4, stream);
  hipMemsetAsync(Tacc, 0, NH * NN * 4, stream);
  hipMemsetAsync(Scol, 0, NH * OUTD * 4, stream);
  hipMemsetAsync(counts, 0, NN * 4, stream);

  cast_x_kernel<<<4096, 256, 0, stream>>>(x, xb);
  transpose_w_kernel<<<dim3(32, 16, 4), dim3(32, 8), 0, stream>>>(W, wt);
  gemm_kernel<<<dim3(4, 32, 4), 256, 0, stream>>>(xb, wt, Hf, Hb);
  s_kernel<<<4096, 256, 0, stream>>>(Hf, a, s_src, s_dst);
  colsum_kernel<<<64, 256, 0, stream>>>(Hf, Scol);
  edge_a_kernel<<<EE / 256, 256, 0, stream>>>(ei, s_src, s_dst, bitmap, counts, flags, mmax);
  scan_kernel<<<1, 256, 0, stream>>>(counts, offsets, cursor);
  edge_b_kernel<<<EE / 256, 256, 0, stream>>>(ei, flags, s_src, s_dst, mmax, cursor, csr_col,
                                              csr_g, Tacc);
  finalize_kernel<<<NN, 256, 0, stream>>>(Hb, Scol, mmax, Tacc, offsets, counts, csr_col, csr_g,
                                          out);
}

// Round 2
// 259.724 us; speedup vs baseline: 1.0875x; 1.0875x over previous
//
#include <hip/hip_runtime.h>
#include <stdint.h>

#define NN 4096      // nodes
#define EE 131072    // edges
#define IND 1024
#define OUTD 512
#define NH 4

typedef __bf16 bf16x8 __attribute__((ext_vector_type(8)));
typedef float f32x4 __attribute__((ext_vector_type(4)));

__device__ __forceinline__ unsigned short f2bf(float f) {
  unsigned u = __float_as_uint(f);
  u += 0x7FFFu + ((u >> 16) & 1u);   // RNE, data has no NaN
  return (unsigned short)(u >> 16);
}

// ---------------- K1a: cast x -> bf16 ----------------
__global__ void cast_x_kernel(const float* __restrict__ x, unsigned short* __restrict__ xb) {
  int i = blockIdx.x * 256 + threadIdx.x;         // 4 elems/thread
  float4 v = ((const float4*)x)[i];
  ushort4 o;
  o.x = f2bf(v.x); o.y = f2bf(v.y); o.z = f2bf(v.z); o.w = f2bf(v.w);
  ((ushort4*)xb)[i] = o;
}

// ---------------- K1b: W[h][i][o] f32 -> Wt[h][o][i] bf16 (transpose) ----------------
__global__ void transpose_w_kernel(const float* __restrict__ W, unsigned short* __restrict__ Wt) {
  __shared__ float tile[32][33];
  int i0 = blockIdx.x * 32, o0 = blockIdx.y * 32, h = blockIdx.z;
  int tx = threadIdx.x, ty = threadIdx.y;
#pragma unroll
  for (int r = 0; r < 32; r += 8)
    tile[ty + r][tx] = W[((size_t)(h * IND + i0 + ty + r)) * OUTD + o0 + tx];
  __syncthreads();
#pragma unroll
  for (int r = 0; r < 32; r += 8)
    Wt[((size_t)(h * OUTD + o0 + ty + r)) * IND + i0 + tx] = f2bf(tile[tx][ty + r]);
}

// ---------------- K2: bf16 MFMA GEMM 128x128, BK=32, 2-phase dbuf, FUSED epilogue ----------------
// Epilogue fuses: Hb write (interleaved [node][head][out]), s_src/s_dst = h.a (row-reduce),
// Scol = column sums (col-reduce). Hf (f32 h) is never materialized.
__device__ __forceinline__ void gload16(const unsigned short* g, unsigned short* l) {
  __builtin_amdgcn_global_load_lds((const __attribute__((address_space(1))) void*)g,
                                   (__attribute__((address_space(3))) void*)l, 16, 0, 0);
}

__global__ __launch_bounds__(256, 2) void gemm_kernel(
    const unsigned short* __restrict__ X, const unsigned short* __restrict__ Wt,
    const float* __restrict__ Av, unsigned short* __restrict__ Hb,
    float* __restrict__ s_src, float* __restrict__ s_dst, float* __restrict__ Scol) {
  __shared__ __align__(16) unsigned short As[2][4096];  // [128 rows][32 k] bf16, XOR-swizzled
  __shared__ __align__(16) unsigned short Bs[2][4096];  // [128 n-rows][32 k]
  const int t = threadIdx.x, w = t >> 6, lane = t & 63;
  const int bx = blockIdx.x, by = blockIdx.y, hh = blockIdx.z;

  const unsigned short* Ab0 = X + (size_t)(by * 128) * IND;
  const unsigned short* Bb0 = Wt + (size_t)(hh * OUTD + bx * 128) * IND;

  // staging map: seg (0..511) -> row=seg>>2, colseg=(seg&3)^(row&3) [both-sides swizzle]
  const int seg0 = w * 64 + lane, seg1 = (4 + w) * 64 + lane;
  const int r0 = seg0 >> 2, c0 = (seg0 & 3) ^ (r0 & 3);
  const int r1 = seg1 >> 2, c1 = (seg1 & 3) ^ (r1 & 3);

  // fragment read byte offsets (per 16B granule, same XOR)
  const int wr = w >> 1, wc = w & 1, g = lane >> 4, rlo = lane & 15;
  int aoff[4], boff[4];
#pragma unroll
  for (int i = 0; i < 4; i++) {
    int ra = wr * 64 + i * 16 + rlo;
    aoff[i] = ra * 64 + ((g ^ (ra & 3)) << 4);
    int rb = wc * 64 + i * 16 + rlo;
    boff[i] = rb * 64 + ((g ^ (rb & 3)) << 4);
  }

  f32x4 zero = {0.f, 0.f, 0.f, 0.f};
  f32x4 acc[4][4];
#pragma unroll
  for (int i = 0; i < 4; i++)
#pragma unroll
    for (int j = 0; j < 4; j++) acc[i][j] = zero;

#define STAGE(buf, kt)                                                   \
  do {                                                                   \
    const unsigned short* ga = Ab0 + (kt) * 32;                          \
    const unsigned short* gb = Bb0 + (kt) * 32;                          \
    gload16(ga + r0 * IND + c0 * 8, &As[buf][w * 512]);                  \
    gload16(ga + r1 * IND + c1 * 8, &As[buf][(4 + w) * 512]);            \
    gload16(gb + r0 * IND + c0 * 8, &Bs[buf][w * 512]);                  \
    gload16(gb + r1 * IND + c1 * 8, &Bs[buf][(4 + w) * 512]);            \
  } while (0)

  STAGE(0, 0);
  __syncthreads();
  int cur = 0;
  for (int kt = 0; kt < 32; ++kt) {
    if (kt != 31) STAGE(cur ^ 1, kt + 1);
    const char* Abuf = (const char*)As[cur];
    const char* Bbuf = (const char*)Bs[cur];
    bf16x8 av[4], bv[4];
#pragma unroll
    for (int i = 0; i < 4; i++) {
      av[i] = *(const bf16x8*)(Abuf + aoff[i]);
      bv[i] = *(const bf16x8*)(Bbuf + boff[i]);
    }
#pragma unroll
    for (int i = 0; i < 4; i++)
#pragma unroll
      for (int j = 0; j < 4; j++)
        acc[i][j] = __builtin_amdgcn_mfma_f32_16x16x32_bf16(av[i], bv[j], acc[i][j], 0, 0, 0);
    __syncthreads();
    cur ^= 1;
  }
#undef STAGE

  // ---- epilogue. C/D layout: col = lane&15 (rlo), row = (lane>>4)*4+q  [m89/m91 verified]
  // Hb interleaved [node][head][out] so finalize reads one contiguous 4KB block per edge.
#pragma unroll
  for (int i = 0; i < 4; i++)
#pragma unroll
    for (int j = 0; j < 4; j++) {
      int mm0 = by * 128 + wr * 64 + i * 16 + g * 4;
      int nn = bx * 128 + wc * 64 + j * 16 + rlo;
#pragma unroll
      for (int q = 0; q < 4; q++)
        Hb[((size_t)(mm0 + q) * NH + hh) * OUTD + nn] = f2bf(acc[i][j][q]);
    }

  // s_src/s_dst: per-row dot with a_src/a_dst. Rows live on (i,q,g); cols on (j,rlo).
  float as_[4], ad_[4];
#pragma unroll
  for (int j = 0; j < 4; j++) {
    int nn = bx * 128 + wc * 64 + j * 16 + rlo;
    as_[j] = Av[hh * 2 * OUTD + nn];
    ad_[j] = Av[hh * 2 * OUTD + OUTD + nn];
  }
#pragma unroll
  for (int i = 0; i < 4; i++)
#pragma unroll
    for (int q = 0; q < 4; q++) {
      float vs = 0.f, vd = 0.f;
#pragma unroll
      for (int j = 0; j < 4; j++) {
        float tv = acc[i][j][q];
        vs += tv * as_[j];
        vd += tv * ad_[j];
      }
#pragma unroll
      for (int m = 1; m < 16; m <<= 1) {
        vs += __shfl_xor(vs, m);
        vd += __shfl_xor(vd, m);
      }
      if (rlo == 0) {
        int r = by * 128 + wr * 64 + i * 16 + g * 4 + q;
        atomicAdd(&s_src[hh * NN + r], vs);
        atomicAdd(&s_dst[hh * NN + r], vd);
      }
    }

  // Scol: column sums. Reduce over g-groups (lanes ^16, ^32).
#pragma unroll
  for (int j = 0; j < 4; j++) {
    float cv = 0.f;
#pragma unroll
    for (int i = 0; i < 4; i++)
#pragma unroll
      for (int q = 0; q < 4; q++) cv += acc[i][j][q];
    cv += __shfl_xor(cv, 16);
    cv += __shfl_xor(cv, 32);
    if (g == 0) {
      int nn = bx * 128 + wc * 64 + j * 16 + rlo;
      atomicAdd(&Scol[hh * OUTD + nn], cv);
    }
  }
}

// ---------------- K4: edge pass A — dedup, counts, row max ----------------
__global__ void edge_a_kernel(const int* __restrict__ ei, const float* __restrict__ s_src,
                              const float* __restrict__ s_dst, unsigned* __restrict__ bitmap,
                              int* __restrict__ counts, int* __restrict__ flags,
                              unsigned* __restrict__ mmax) {
  int e = blockIdx.x * 256 + threadIdx.x;
  int row = ei[e], col = ei[EE + e];
  unsigned key = ((unsigned)row << 12) | (unsigned)col;
  unsigned bit = 1u << (key & 31);
  unsigned old = atomicOr(&bitmap[key >> 5], bit);
  if (old & bit) { flags[e] = 1; return; }   // duplicate (same e value -> any winner ok)
  flags[e] = 0;
  atomicAdd(&counts[row], 1);
#pragma unroll
  for (int h = 0; h < NH; h++) {
    float eh = s_src[h * NN + row] + s_dst[h * NN + col];
    eh = eh > 0.f ? eh : 0.2f * eh;
    if (eh > 0.f) atomicMax(&mmax[h * NN + row], __float_as_uint(eh)); // nonneg floats: uint-monotone
  }
}

// ---------------- K5: exclusive scan of counts (single block) ----------------
__global__ void scan_kernel(const int* __restrict__ counts, int* __restrict__ offsets,
                            int* __restrict__ cursor) {
  __shared__ int part[256];
  int t = threadIdx.x;
  int local[16];
  int s = 0;
#pragma unroll
  for (int k = 0; k < 16; k++) { local[k] = counts[t * 16 + k]; s += local[k]; }
  part[t] = s;
  __syncthreads();
  if (t == 0) {
    int run = 0;
    for (int i = 0; i < 256; i++) { int v = part[i]; part[i] = run; run += v; }
  }
  __syncthreads();
  int off = part[t];
#pragma unroll
  for (int k = 0; k < 16; k++) {
    offsets[t * 16 + k] = off;
    cursor[t * 16 + k] = off;
    off += local[k];
  }
}

// ---------------- K6: edge pass B — CSR scatter + g coeffs + T sums ----------------
__global__ void edge_b_kernel(const int* __restrict__ ei, const int* __restrict__ flags,
                              const float* __restrict__ s_src, const float* __restrict__ s_dst,
                              const unsigned* __restrict__ mmax, int* __restrict__ cursor,
                              int* __restrict__ csr_col, float* __restrict__ csr_g,
                              float* __restrict__ Tacc) {
  int e = blockIdx.x * 256 + threadIdx.x;
  if (flags[e]) return;
  int row = ei[e], col = ei[EE + e];
  int pos = atomicAdd(&cursor[row], 1);
  csr_col[pos] = col;
#pragma unroll
  for (int h = 0; h < NH; h++) {
    float eh = s_src[h * NN + row] + s_dst[h * NN + col];
    eh = eh > 0.f ? eh : 0.2f * eh;
    float mm = __uint_as_float(mmax[h * NN + row]);
    float gg = expf(eh - mm) - expf(-mm);
    csr_g[h * EE + pos] = gg;
    atomicAdd(&Tacc[h * NN + row], gg);
  }
}

// ---------------- K7: finalize — wave w = head w; one dwordx4 (8 bf16) per edge per wave ----
__global__ __launch_bounds__(256) void finalize_kernel(
    const unsigned short* __restrict__ Hb,   // [node][head][out] bf16
    const float* __restrict__ S, const unsigned* __restrict__ mmax,
    const float* __restrict__ Tacc, const int* __restrict__ offsets,
    const int* __restrict__ counts, const int* __restrict__ csr_col,
    const float* __restrict__ csr_g, float* __restrict__ out) {
  __shared__ int cols_s[64];
  __shared__ float g_s[4][64];
  const int i = blockIdx.x, t = threadIdx.x;
  const int w = t >> 6, lane = t & 63;   // wave w handles head w

  float mm = __uint_as_float(mmax[w * NN + i]);
  float ch = expf(-mm);
  float D = (float)NN * ch + Tacc[w * NN + i];
  float inv = 1.0f / D;

  float acc[8];
  {
    const float4* Sv = (const float4*)(S + w * OUTD + lane * 8);
    float4 s0 = Sv[0], s1 = Sv[1];
    acc[0] = ch * s0.x; acc[1] = ch * s0.y; acc[2] = ch * s0.z; acc[3] = ch * s0.w;
    acc[4] = ch * s1.x; acc[5] = ch * s1.y; acc[6] = ch * s1.z; acc[7] = ch * s1.w;
  }

  const int start = offsets[i], cnt = counts[i];
  for (int base = 0; base < cnt; base += 64) {
    int nload = min(64, cnt - base);
    __syncthreads();
    if (w == 0) cols_s[lane] = (lane < nload) ? csr_col[start + base + lane] : 0;
    g_s[w][lane] = (lane < nload) ? csr_g[w * EE + start + base + lane] : 0.f;
    __syncthreads();
#pragma unroll 2
    for (int k = 0; k < nload; k++) {
      int cc = cols_s[k];
      float gg = g_s[w][k];
      uint4 u = *(const uint4*)(Hb + ((size_t)(cc * NH + w)) * OUTD + lane * 8);
      acc[0] += gg * __uint_as_float(u.x << 16);
      acc[1] += gg * __uint_as_float(u.x & 0xffff0000u);
      acc[2] += gg * __uint_as_float(u.y << 16);
      acc[3] += gg * __uint_as_float(u.y & 0xffff0000u);
      acc[4] += gg * __uint_as_float(u.z << 16);
      acc[5] += gg * __uint_as_float(u.z & 0xffff0000u);
      acc[6] += gg * __uint_as_float(u.w << 16);
      acc[7] += gg * __uint_as_float(u.w & 0xffff0000u);
    }
  }

  float4 o0, o1;
  o0.x = acc[0] * inv; o0.y = acc[1] * inv; o0.z = acc[2] * inv; o0.w = acc[3] * inv;
  o1.x = acc[4] * inv; o1.y = acc[5] * inv; o1.z = acc[6] * inv; o1.w = acc[7] * inv;
  float* ob = out + (size_t)i * (NH * OUTD) + w * OUTD + lane * 8;
  ((float4*)ob)[0] = o0;
  ((float4*)ob)[1] = o1;
}

extern "C" void kernel_launch(void* const* d_in, const int* in_sizes, int n_in,
                              void* d_out, int out_size, void* d_ws, size_t ws_size,
                              hipStream_t stream) {
  const float* x = (const float*)d_in[0];
  const int* ei = (const int*)d_in[1];
  const float* W = (const float*)d_in[2];
  const float* a = (const float*)d_in[3];
  float* out = (float*)d_out;

  char* ws = (char*)d_ws;
  unsigned short* xb = (unsigned short*)(ws);                       // 8 MB
  unsigned short* wt = (unsigned short*)(ws + (8ull << 20));        // 4 MB
  unsigned short* Hb = (unsigned short*)(ws + (12ull << 20));       // 16 MB  [node][head][out]
  char* scal = ws + (28ull << 20);
  float* s_src = (float*)(scal);                                    // 64 KB (zeroed)
  float* s_dst = (float*)(scal + 1 * 65536);                        // 64 KB (zeroed)
  unsigned* mmax = (unsigned*)(scal + 2 * 65536);                   // 64 KB (zeroed)
  float* Tacc = (float*)(scal + 3 * 65536);                         // 64 KB (zeroed)
  float* Scol = (float*)(scal + 4 * 65536);                         // 8 KB (zeroed)
  int* flags = (int*)(ws + (29ull << 20));                          // 512 KB
  unsigned* bitmap = (unsigned*)(ws + (30ull << 20));               // 2 MB (zeroed)
  int* counts = (int*)(ws + (32ull << 20));                         // 16 KB (zeroed)
  int* offsets = (int*)(ws + (32ull << 20) + 65536);                // 16 KB
  int* cursor = (int*)(ws + (32ull << 20) + 2 * 65536);             // 16 KB
  int* csr_col = (int*)(ws + (33ull << 20));                        // 512 KB
  float* csr_g = (float*)(ws + (34ull << 20));                      // 2 MB   (total 36 MB)

  hipMemsetAsync(scal, 0, 4 * 65536 + 8192, stream);                // s_src,s_dst,mmax,Tacc,Scol
  hipMemsetAsync(bitmap, 0, (size_t)NN * NN / 8, stream);
  hipMemsetAsync(counts, 0, NN * 4, stream);

  cast_x_kernel<<<4096, 256, 0, stream>>>(x, xb);
  transpose_w_kernel<<<dim3(32, 16, 4), dim3(32, 8), 0, stream>>>(W, wt);
  gemm_kernel<<<dim3(4, 32, 4), 256, 0, stream>>>(xb, wt, a, Hb, s_src, s_dst, Scol);
  edge_a_kernel<<<EE / 256, 256, 0, stream>>>(ei, s_src, s_dst, bitmap, counts, flags, mmax);
  scan_kernel<<<1, 256, 0, stream>>>(counts, offsets, cursor);
  edge_b_kernel<<<EE / 256, 256, 0, stream>>>(ei, flags, s_src, s_dst, mmax, cursor, csr_col,
                                              csr_g, Tacc);
  finalize_kernel<<<NN, 256, 0, stream>>>(Hb, Scol, mmax, Tacc, offsets, counts, csr_col, csr_g,
                                          out);
}